// Round 10
// baseline (355.396 us; speedup 1.0000x reference)
//
#include <hip/hip_runtime.h>

// GCN 4-layer forward on MI355X.
// Reference: h' = relu( norm_dst * segsum_{dst}( ((h*norm_src) @ W)[src] ) + b )
//
// Round 10:
//  - Fused deg+gemm0: atomics DISTRIBUTED across all 782 tile-blocks (3
//    edges/thread before the tile) instead of 256 dedicated blocks — r9's
//    fused dispatch was atomic-drain-bound at 76us because only 1/4 of the
//    grid issued atomics; full-grid issue restores the ~23G/s drain rate and
//    the le-store waits hide under other waves' FMAs.
//  - Gather: 2048 blocks x wave-stride (~6 nodes/wave) instead of 12500
//    one-shot blocks (r2 counters: nothing saturated -> issue/dispatch bound).

namespace {

constexpr int NN = 50000;      // nodes
constexpr int NE = 600000;     // edges
constexpr int SCAN_BLK = 256;
constexpr int NBLK = (NN + SCAN_BLK - 1) / SCAN_BLK;  // 196
constexpr int GEMM_TILES = (NN + 63) / 64;            // 782
constexpr int EPB = (NE + GEMM_TILES - 1) / GEMM_TILES;  // 768 edges per block

__global__ void norm_kernel(const int* __restrict__ dego, const int* __restrict__ degi,
                            float* __restrict__ ns, float* __restrict__ nd) {
  int i = blockIdx.x * blockDim.x + threadIdx.x;
  if (i < NN) {
    int a = dego[i]; if (a < 1) a = 1;
    int b = degi[i]; if (b < 1) b = 1;
    ns[i] = 1.0f / sqrtf((float)a);
    nd[i] = 1.0f / sqrtf((float)b);
  }
}

// --- 3-phase scan of degi[NN] -> rowptr[NN+1] (exclusive) ---

__global__ __launch_bounds__(SCAN_BLK) void scan_phase1(const int* __restrict__ deg,
                                                        int* __restrict__ bsum) {
  __shared__ int ws[SCAN_BLK / 64];
  int i = blockIdx.x * SCAN_BLK + threadIdx.x;
  int v = (i < NN) ? deg[i] : 0;
#pragma unroll
  for (int off = 32; off; off >>= 1) v += __shfl_down(v, off, 64);
  int lane = threadIdx.x & 63, w = threadIdx.x >> 6;
  if (lane == 0) ws[w] = v;
  __syncthreads();
  if (threadIdx.x == 0) {
    int s = 0;
#pragma unroll
    for (int k = 0; k < SCAN_BLK / 64; ++k) s += ws[k];
    bsum[blockIdx.x] = s;
  }
}

__global__ __launch_bounds__(256) void scan_phase2(const int* __restrict__ bsum,
                                                   int* __restrict__ bpre,
                                                   int* __restrict__ rowptr) {
  __shared__ int s[256];
  int t = threadIdx.x;
  int v = (t < NBLK) ? bsum[t] : 0;
  s[t] = v;
  __syncthreads();
  for (int off = 1; off < 256; off <<= 1) {
    int u = (t >= off) ? s[t - off] : 0;
    __syncthreads();
    s[t] += u;
    __syncthreads();
  }
  if (t < NBLK) bpre[t] = s[t] - v;  // exclusive
  if (t == 255) rowptr[NN] = s[255]; // total == NE
}

__global__ __launch_bounds__(SCAN_BLK) void scan_phase3(const int* __restrict__ deg,
                                                        const int* __restrict__ bpre,
                                                        int* __restrict__ rowptr) {
  __shared__ int s[SCAN_BLK];
  int t = threadIdx.x;
  int i = blockIdx.x * SCAN_BLK + t;
  int v = (i < NN) ? deg[i] : 0;
  s[t] = v;
  __syncthreads();
  for (int off = 1; off < SCAN_BLK; off <<= 1) {
    int u = (t >= off) ? s[t - off] : 0;
    __syncthreads();
    s[t] += u;
    __syncthreads();
  }
  if (i < NN) rowptr[i] = bpre[blockIdx.x] + s[t] - v;
}

// atomic-free CSR fill using le slots recorded during counting
__global__ void scatter_kernel(const int* __restrict__ src, const int* __restrict__ dst,
                               const int* __restrict__ le, const int* __restrict__ rowptr,
                               int* __restrict__ col) {
  int e = blockIdx.x * blockDim.x + threadIdx.x;
  if (e < NE) col[rowptr[dst[e]] + le[e]] = src[e];
}

// ---- GEMM tile body ----
// x[row][j] = sum_k (opt ns[row] *) h[row][k] * W[k][j]    K = 128
// 64 rows x DO cols per tile; 256 threads = 16rq x 16cq, 4x4 per col-half.
// hs[64][132] row-major (coalesced staging, padded: conflict-free b128);
// wl[128][64] per half (2-way broadcast reads, free). 66.5KB LDS, 2 blk/CU.
template <int DO, bool USE_NS>
__device__ void gemm_body(const float* __restrict__ h, const float* __restrict__ W,
                          const float* __restrict__ ns, float* __restrict__ x,
                          int row0) {
  constexpr int CH = DO / 64;
  __shared__ __align__(16) float hs[64 * 132];  // 33.8 KB
  __shared__ __align__(16) float wl[128 * 64];  // 32 KB
  const int tid = threadIdx.x;

  // stage hs (optionally ns-folded): coalesced (32 lanes x float4 per row)
#pragma unroll
  for (int it = 0; it < 8; ++it) {
    int flat = it * 256 + tid;
    int row = flat >> 5;
    int c = flat & 31;
    int grow = row0 + row;
    float4 hv = make_float4(0.f, 0.f, 0.f, 0.f);
    float sc = 0.f;
    if (grow < NN) {
      hv = *reinterpret_cast<const float4*>(&h[(size_t)grow * 128 + c * 4]);
      sc = USE_NS ? ns[grow] : 1.0f;
    }
    float* d = &hs[row * 132 + c * 4];
    d[0] = hv.x * sc; d[1] = hv.y * sc; d[2] = hv.z * sc; d[3] = hv.w * sc;
  }

  const int rq = tid >> 4;
  const int cq = tid & 15;

  for (int ch = 0; ch < CH; ++ch) {
    __syncthreads();  // ch=0: hs ready; ch>0: wl no longer being read
#pragma unroll
    for (int it = 0; it < 8; ++it) {
      int flat = it * 256 + tid;
      int k = flat >> 4;
      int c4 = flat & 15;
      *reinterpret_cast<float4*>(&wl[k * 64 + c4 * 4]) =
          *reinterpret_cast<const float4*>(&W[k * DO + ch * 64 + c4 * 4]);
    }
    __syncthreads();

    float acc[4][4] = {{0.f}};
#pragma unroll 4
    for (int k4 = 0; k4 < 32; ++k4) {
      float hv[4][4], wv[4][4];
#pragma unroll
      for (int i = 0; i < 4; ++i) {
        float4 t = *reinterpret_cast<const float4*>(&hs[(rq * 4 + i) * 132 + k4 * 4]);
        hv[i][0] = t.x; hv[i][1] = t.y; hv[i][2] = t.z; hv[i][3] = t.w;
      }
#pragma unroll
      for (int kk = 0; kk < 4; ++kk) {
        float4 t = *reinterpret_cast<const float4*>(&wl[(k4 * 4 + kk) * 64 + cq * 4]);
        wv[kk][0] = t.x; wv[kk][1] = t.y; wv[kk][2] = t.z; wv[kk][3] = t.w;
      }
#pragma unroll
      for (int i = 0; i < 4; ++i)
#pragma unroll
        for (int kk = 0; kk < 4; ++kk)
#pragma unroll
          for (int j = 0; j < 4; ++j)
            acc[i][j] = fmaf(hv[i][kk], wv[kk][j], acc[i][j]);
    }

#pragma unroll
    for (int i = 0; i < 4; ++i) {
      int row = row0 + rq * 4 + i;
      if (row < NN) {
        *reinterpret_cast<float4*>(&x[(size_t)row * DO + ch * 64 + cq * 4]) =
            make_float4(acc[i][0], acc[i][1], acc[i][2], acc[i][3]);
      }
    }
  }
}

// Fused: every block fires its ~768-edge atomic slice (3 edges/thread: 2
// histogram atomics + dependent le store), then runs its layer-0 GEMM tile
// (x0 = h0 @ W0, UNSCALED — ns folded into gather-0). Atomic drain proceeds
// at full-grid issue rate while FMAs run; le-store waits hide under other
// waves' compute on the same CU.
__global__ __launch_bounds__(256, 2) void gemm0_deg_kernel(
    const float* __restrict__ h, const float* __restrict__ W,
    float* __restrict__ x,
    const int* __restrict__ src, const int* __restrict__ dst,
    int* __restrict__ dego, int* __restrict__ degi, int* __restrict__ le) {
  const int e0 = blockIdx.x * EPB;
  const int e1 = (e0 + EPB < NE) ? (e0 + EPB) : NE;
#pragma unroll
  for (int q = 0; q < 3; ++q) {           // EPB = 768 = 3 * 256
    int e = e0 + q * 256 + threadIdx.x;
    if (e < e1) {
      atomicAdd(&dego[src[e]], 1);
      le[e] = atomicAdd(&degi[dst[e]], 1);
    }
  }
  gemm_body<128, false>(h, W, nullptr, x, blockIdx.x * 64);
}

template <int DO>
__global__ __launch_bounds__(256, 2) void gemm_ns(const float* __restrict__ h,
                                                  const float* __restrict__ W,
                                                  const float* __restrict__ ns,
                                                  float* __restrict__ x) {
  gemm_body<DO, true>(h, W, ns, x, blockIdx.x * 64);
}

// Wave-stride gather: each wave processes multiple dst nodes. Lane layout per
// node: sub = lane/LPR edge slot, c4 = (lane%LPR)*4 column; EPW edge slots, 4
// edges/slot in flight. NSRC: scale each edge row by ns[col] (layer 0 only).
// Slot partials combined by shfl_xor; lanes < LPR write float4 out with
// nd/bias/relu fused.
template <int D, bool RELU, bool NSRC>
__global__ __launch_bounds__(256) void gather_kernel(const float* __restrict__ x,
                                                     const int* __restrict__ rowptr,
                                                     const int* __restrict__ col,
                                                     const float* __restrict__ nd,
                                                     const float* __restrict__ b,
                                                     const float* __restrict__ nsv,
                                                     float* __restrict__ out) {
  constexpr int LPR = D / 4;     // 32 (D=128) or 16 (D=64)
  constexpr int EPW = 64 / LPR;  // 2 or 4
  const int lane = threadIdx.x & 63;
  const int sub = lane / LPR;
  const int c4 = (lane % LPR) * 4;
  const int nwaves = gridDim.x * (blockDim.x >> 6);
  const int wave0 = (blockIdx.x * blockDim.x + threadIdx.x) >> 6;

  // bias is loop-invariant
  float4 bb = *reinterpret_cast<const float4*>(&b[c4]);

  for (int wid = wave0; wid < NN; wid += nwaves) {
    const int beg = rowptr[wid];
    const int end = rowptr[wid + 1];

    float ax = 0.f, ay = 0.f, az = 0.f, aw = 0.f;
    int e = beg + sub;
    for (; e + 3 * EPW < end; e += 4 * EPW) {
      int c0 = col[e];
      int c1 = col[e + EPW];
      int c2 = col[e + 2 * EPW];
      int c3 = col[e + 3 * EPW];
      float s0 = NSRC ? nsv[c0] : 1.0f;
      float s1 = NSRC ? nsv[c1] : 1.0f;
      float s2 = NSRC ? nsv[c2] : 1.0f;
      float s3 = NSRC ? nsv[c3] : 1.0f;
      float4 v0 = *reinterpret_cast<const float4*>(&x[(size_t)c0 * D + c4]);
      float4 v1 = *reinterpret_cast<const float4*>(&x[(size_t)c1 * D + c4]);
      float4 v2 = *reinterpret_cast<const float4*>(&x[(size_t)c2 * D + c4]);
      float4 v3 = *reinterpret_cast<const float4*>(&x[(size_t)c3 * D + c4]);
      if (NSRC) {
        ax = fmaf(s0, v0.x, fmaf(s1, v1.x, fmaf(s2, v2.x, fmaf(s3, v3.x, ax))));
        ay = fmaf(s0, v0.y, fmaf(s1, v1.y, fmaf(s2, v2.y, fmaf(s3, v3.y, ay))));
        az = fmaf(s0, v0.z, fmaf(s1, v1.z, fmaf(s2, v2.z, fmaf(s3, v3.z, az))));
        aw = fmaf(s0, v0.w, fmaf(s1, v1.w, fmaf(s2, v2.w, fmaf(s3, v3.w, aw))));
      } else {
        ax += (v0.x + v1.x) + (v2.x + v3.x);
        ay += (v0.y + v1.y) + (v2.y + v3.y);
        az += (v0.z + v1.z) + (v2.z + v3.z);
        aw += (v0.w + v1.w) + (v2.w + v3.w);
      }
    }
    for (; e < end; e += EPW) {
      int c0 = col[e];
      float s0 = NSRC ? nsv[c0] : 1.0f;
      float4 v0 = *reinterpret_cast<const float4*>(&x[(size_t)c0 * D + c4]);
      ax = fmaf(s0, v0.x, ax);
      ay = fmaf(s0, v0.y, ay);
      az = fmaf(s0, v0.z, az);
      aw = fmaf(s0, v0.w, aw);
    }

#pragma unroll
    for (int off = LPR; off < 64; off <<= 1) {
      ax += __shfl_xor(ax, off, 64);
      ay += __shfl_xor(ay, off, 64);
      az += __shfl_xor(az, off, 64);
      aw += __shfl_xor(aw, off, 64);
    }

    if (lane < LPR) {
      const float s = nd[wid];
      float4 r;
      r.x = fmaf(ax, s, bb.x);
      r.y = fmaf(ay, s, bb.y);
      r.z = fmaf(az, s, bb.z);
      r.w = fmaf(aw, s, bb.w);
      if (RELU) {
        r.x = fmaxf(r.x, 0.f);
        r.y = fmaxf(r.y, 0.f);
        r.z = fmaxf(r.z, 0.f);
        r.w = fmaxf(r.w, 0.f);
      }
      *reinterpret_cast<float4*>(&out[(size_t)wid * D + c4]) = r;
    }
  }
}

}  // namespace

extern "C" void kernel_launch(void* const* d_in, const int* in_sizes, int n_in,
                              void* d_out, int out_size, void* d_ws, size_t ws_size,
                              hipStream_t stream) {
  const float* h0  = (const float*)d_in[0];
  const int*   src = (const int*)d_in[1];
  const int*   dst = (const int*)d_in[2];
  const float* W0 = (const float*)d_in[3];
  const float* b0 = (const float*)d_in[4];
  const float* W1 = (const float*)d_in[5];
  const float* b1 = (const float*)d_in[6];
  const float* W2 = (const float*)d_in[7];
  const float* b2 = (const float*)d_in[8];
  const float* W3 = (const float*)d_in[9];
  const float* b3 = (const float*)d_in[10];
  float* out = (float*)d_out;

  // workspace layout (256B aligned)
  char* w = (char*)d_ws;
  size_t off = 0;
  auto take = [&](size_t bytes) {
    char* p = w + off;
    off = (off + bytes + 255) & ~size_t(255);
    return p;
  };
  int*   deg_out = (int*)take(NN * 4);   // adjacent: one memset covers both
  int*   deg_in  = (int*)take(NN * 4);
  float* nsrc    = (float*)take(NN * 4);
  float* ndst    = (float*)take(NN * 4);
  int*   rowptr  = (int*)take((NN + 1) * 4);
  int*   le      = (int*)take(NE * 4);
  int*   col     = (int*)take(NE * 4);
  int*   bsum    = (int*)take(NBLK * 4);
  int*   bpre    = (int*)take(NBLK * 4);
  float* xbuf    = (float*)take((size_t)NN * 128 * 4);
  float* hbuf    = (float*)take((size_t)NN * 128 * 4);
  (void)ws_size; (void)in_sizes; (void)n_in; (void)out_size;

  // zero both degree arrays (contiguous)
  hipMemsetAsync(deg_out, 0, (size_t)((char*)nsrc - (char*)deg_out), stream);

  const int EB = (NE + 255) / 256;
  const int NB = (NN + 255) / 256;

  // fused: per-block edge atomics + layer-0 GEMM x0 = h0@W0 (unscaled)
  gemm0_deg_kernel<<<GEMM_TILES, 256, 0, stream>>>(
      h0, W0, xbuf, src, dst, deg_out, deg_in, le);
  norm_kernel<<<NB, 256, 0, stream>>>(deg_out, deg_in, nsrc, ndst);
  scan_phase1<<<NBLK, SCAN_BLK, 0, stream>>>(deg_in, bsum);
  scan_phase2<<<1, 256, 0, stream>>>(bsum, bpre, rowptr);
  scan_phase3<<<NBLK, SCAN_BLK, 0, stream>>>(deg_in, bpre, rowptr);
  scatter_kernel<<<EB, 256, 0, stream>>>(src, dst, le, rowptr, col);

  const int GATHER_BLOCKS = 2048;  // wave-stride: 8192 waves, ~6 nodes each

  // layer 0: x0 unscaled -> gather applies ns[col] inside the sum
  gather_kernel<128, true, true><<<GATHER_BLOCKS, 256, 0, stream>>>(
      xbuf, rowptr, col, ndst, b0, nsrc, hbuf);
  // layer 1
  gemm_ns<128><<<GEMM_TILES, 256, 0, stream>>>(hbuf, W1, nsrc, xbuf);
  gather_kernel<128, true, false><<<GATHER_BLOCKS, 256, 0, stream>>>(
      xbuf, rowptr, col, ndst, b1, nullptr, hbuf);
  // layer 2
  gemm_ns<128><<<GEMM_TILES, 256, 0, stream>>>(hbuf, W2, nsrc, xbuf);
  gather_kernel<128, true, false><<<GATHER_BLOCKS, 256, 0, stream>>>(
      xbuf, rowptr, col, ndst, b2, nullptr, hbuf);
  // layer 3: no relu, D=64, straight to d_out
  gemm_ns<64><<<GEMM_TILES, 256, 0, stream>>>(hbuf, W3, nsrc, xbuf);
  gather_kernel<64, false, false><<<GATHER_BLOCKS, 256, 0, stream>>>(
      xbuf, rowptr, col, ndst, b3, nullptr, out);
}